// Round 4
// baseline (625.223 us; speedup 1.0000x reference)
//
#include <hip/hip_runtime.h>

#define EMB_D 64

typedef float float4v __attribute__((ext_vector_type(4)));

// ---------------------------------------------------------------------------
// fused degree kernel: bipartite degrees (deg1, both directions) + s-row
// degrees (deg2, item-indexed)
// ---------------------------------------------------------------------------
__global__ void deg_fused_kernel(const int* __restrict__ eu, const int* __restrict__ ei,
                                 int E, int U,
                                 const int* __restrict__ sr, int S,
                                 int* __restrict__ deg1, int* __restrict__ deg2) {
    int e = blockIdx.x * blockDim.x + threadIdx.x;
    if (e < E) {
        atomicAdd(&deg1[eu[e]], 1);
        atomicAdd(&deg1[U + ei[e]], 1);
    }
    if (e < S) {
        atomicAdd(&deg2[sr[e]], 1);
    }
}

// norm[m] = rsqrt(deg1[m] + 1)
__global__ void norm_kernel(const int* __restrict__ deg, float* __restrict__ norm, int M) {
    int m = blockIdx.x * blockDim.x + threadIdx.x;
    if (m < M) norm[m] = rsqrtf((float)deg[m] + 1.0f);
}

// ---------------------------------------------------------------------------
// 3-kernel exclusive scan of deg[n] -> rowptr[n+1], cursor[n]
// ---------------------------------------------------------------------------
__global__ void __launch_bounds__(1024) scan_block(const int* __restrict__ deg,
                                                   int* __restrict__ incl,
                                                   int* __restrict__ bsum, int n) {
    __shared__ int sh[1024];
    int i = blockIdx.x * 1024 + threadIdx.x;
    int v = (i < n) ? deg[i] : 0;
    sh[threadIdx.x] = v;
    __syncthreads();
    for (int ofs = 1; ofs < 1024; ofs <<= 1) {
        int t = (threadIdx.x >= ofs) ? sh[threadIdx.x - ofs] : 0;
        __syncthreads();
        sh[threadIdx.x] += t;
        __syncthreads();
    }
    if (i < n) incl[i] = sh[threadIdx.x];
    if (threadIdx.x == 1023) bsum[blockIdx.x] = sh[1023];
}

__global__ void __launch_bounds__(256) scan_bsum(int* __restrict__ bsum, int nb) {
    __shared__ int sh[256];
    int v = (threadIdx.x < nb) ? bsum[threadIdx.x] : 0;
    sh[threadIdx.x] = v;
    __syncthreads();
    for (int ofs = 1; ofs < 256; ofs <<= 1) {
        int t = (threadIdx.x >= ofs) ? sh[threadIdx.x - ofs] : 0;
        __syncthreads();
        sh[threadIdx.x] += t;
        __syncthreads();
    }
    if (threadIdx.x < nb) bsum[threadIdx.x] = sh[threadIdx.x] - v;  // exclusive
}

__global__ void finalize_rowptr(const int* __restrict__ incl, const int* __restrict__ deg,
                                const int* __restrict__ bsum, int* __restrict__ rowptr,
                                int* __restrict__ cursor, int n) {
    int i = blockIdx.x * blockDim.x + threadIdx.x;
    if (i < n) {
        int v = incl[i] - deg[i] + bsum[i >> 10];
        rowptr[i] = v;
        cursor[i] = v;
    } else if (i == n) {
        rowptr[n] = incl[n - 1] + bsum[(n - 1) >> 10];
    }
}

// ---------------------------------------------------------------------------
// scatter bipartite edges: cols only (4B entries), no weights needed here
// ---------------------------------------------------------------------------
__global__ void scatter_bip(const int* __restrict__ eu, const int* __restrict__ ei,
                            int E, int U,
                            int* __restrict__ cursor1, int* __restrict__ col1) {
    int e = blockIdx.x * blockDim.x + threadIdx.x;
    if (e >= E) return;
    int u  = eu[e];
    int iv = U + ei[e];
    int p1 = atomicAdd(&cursor1[u], 1);
    int p2 = atomicAdd(&cursor1[iv], 1);
    col1[p1] = iv;
    col1[p2] = u;
}

// scatter s-edges: packed (col, w_bits), item-row indexed
__global__ void scatter_s(const int* __restrict__ sr, const int* __restrict__ sc,
                          const float* __restrict__ sv, int S, int U,
                          int* __restrict__ cursor2, int2* __restrict__ ent2) {
    int e = blockIdx.x * blockDim.x + threadIdx.x;
    if (e >= S) return;
    int p = atomicAdd(&cursor2[sr[e]], 1);
    ent2[p] = make_int2(U + sc[e], __float_as_int(sv[e]));
}

// ---------------------------------------------------------------------------
// cur = concat(user_emb, item_emb)   (float4, no out write)
// ---------------------------------------------------------------------------
__global__ void init_kernel(const float4v* __restrict__ ue, const float4v* __restrict__ ie,
                            long u4, long total4, float4v* __restrict__ cur) {
    long stride = (long)gridDim.x * blockDim.x;
    for (long idx = (long)blockIdx.x * blockDim.x + threadIdx.x; idx < total4; idx += stride) {
        cur[idx] = (idx < u4) ? ue[idx] : ie[idx - u4];
    }
}

// ---------------------------------------------------------------------------
// gather: one wave per destination node; 4 edge-groups x 16 lanes x float4.
// Bipartite weights recomputed as norm[dst]*norm[col].
// MODE 0: nxt = acc                       (layer 1: e0->e1)
// MODE 1: a0=nxt[o]; b1=cur[o]; nxt=acc; out=a0+b1+acc   (layer 2: partial sum)
// MODE 2: out = 0.25*(out + acc)         (layer 3: final average)
// ---------------------------------------------------------------------------
template <int MODE>
__global__ void __launch_bounds__(256) gather_kernel(const int* __restrict__ rp1,
                                                     const int* __restrict__ ent1,
                                                     const int* __restrict__ rp2,
                                                     const int2* __restrict__ ent2,
                                                     const float* __restrict__ norm,
                                                     const float* __restrict__ cur,
                                                     float* __restrict__ nxt,
                                                     float* __restrict__ out,
                                                     int U, int M) {
    int wid  = (int)((blockIdx.x * (long)blockDim.x + threadIdx.x) >> 6);
    int lane = threadIdx.x & 63;
    int g    = lane >> 4;       // edge group 0..3
    int l    = lane & 15;       // float4 slot within row
    if (wid >= M) return;
    float nd = norm[wid];
    int beg = rp1[wid];
    int end = rp1[wid + 1];

    float4v acc = {0.f, 0.f, 0.f, 0.f};
    int j = beg + g;
    if (j < end) {
        int c0 = ent1[j];
        float4v v0 = ((const float4v*)(cur + (long)c0 * EMB_D))[l];
        float  n0 = norm[c0];
        for (j += 4; j < end; j += 4) {
            int c1 = ent1[j];
            float4v v1 = ((const float4v*)(cur + (long)c1 * EMB_D))[l];
            float  n1 = norm[c1];
            acc += (nd * n0) * v0;
            v0 = v1; n0 = n1;
        }
        acc += (nd * n0) * v0;
    }

    if (wid >= U) {   // item rows also receive s-edges
        int r = wid - U;
        int b2 = rp2[r];
        int e2 = rp2[r + 1];
        j = b2 + g;
        if (j < e2) {
            int2 E0 = ent2[j];
            float4v v0 = ((const float4v*)(cur + (long)E0.x * EMB_D))[l];
            float  w0 = __int_as_float(E0.y);
            for (j += 4; j < e2; j += 4) {
                int2 E1 = ent2[j];
                float4v v1 = ((const float4v*)(cur + (long)E1.x * EMB_D))[l];
                float  w1 = __int_as_float(E1.y);
                acc += w0 * v0;
                v0 = v1; w0 = w1;
            }
            acc += w0 * v0;
        }
    }

    // reduce across the 4 groups
    acc.x += __shfl_xor(acc.x, 16); acc.y += __shfl_xor(acc.y, 16);
    acc.z += __shfl_xor(acc.z, 16); acc.w += __shfl_xor(acc.w, 16);
    acc.x += __shfl_xor(acc.x, 32); acc.y += __shfl_xor(acc.y, 32);
    acc.z += __shfl_xor(acc.z, 32); acc.w += __shfl_xor(acc.w, 32);

    if (g == 0) {
        long o4 = (long)wid * 16 + l;
        if (MODE == 0) {
            ((float4v*)nxt)[o4] = acc;
        } else if (MODE == 1) {
            float4v a0 = ((const float4v*)nxt)[o4];   // e0 (own row, pre-overwrite)
            float4v b1 = ((const float4v*)cur)[o4];   // e1 (own row of cur)
            ((float4v*)nxt)[o4] = acc;                // e2 for next layer's cur
            ((float4v*)out)[o4] = a0 + b1 + acc;      // partial sum e0+e1+e2
        } else {
            float4v p = ((const float4v*)out)[o4];
            ((float4v*)out)[o4] = 0.25f * (p + acc);
        }
    }
}

extern "C" void kernel_launch(void* const* d_in, const int* in_sizes, int n_in,
                              void* d_out, int out_size, void* d_ws, size_t ws_size,
                              hipStream_t stream) {
    const float* user_emb = (const float*)d_in[0];
    const float* item_emb = (const float*)d_in[1];
    const int*   edge_user = (const int*)d_in[2];
    const int*   edge_item = (const int*)d_in[3];
    const int*   s_row = (const int*)d_in[4];
    const int*   s_col = (const int*)d_in[5];
    const float* s_val = (const float*)d_in[6];
    float* out = (float*)d_out;

    const int U = in_sizes[0] / EMB_D;
    const int I = in_sizes[1] / EMB_D;
    const int M = U + I;
    const int E = in_sizes[2];
    const int S = in_sizes[4];
    const long MD = (long)M * EMB_D;
    const long T1 = 2L * E;           // bipartite CSR entries

    // workspace carve-up, 16B-aligned chunks
    char* p = (char*)d_ws;
    auto carve = [&](long bytes) {
        char* q = p;
        p += (bytes + 15) & ~15L;
        return q;
    };
    float* bufA    = (float*)carve(MD * sizeof(float));
    float* bufB    = (float*)carve(MD * sizeof(float));
    float* norm    = (float*)carve((long)M * sizeof(float));
    int*   deg1    = (int*)carve((long)M * sizeof(int));
    int*   deg2    = (int*)carve((long)I * sizeof(int));
    int*   incl    = (int*)carve((long)M * sizeof(int));
    int*   rowptr1 = (int*)carve((long)(M + 1) * sizeof(int));
    int*   cursor1 = (int*)carve((long)M * sizeof(int));
    int*   rowptr2 = (int*)carve((long)(I + 1) * sizeof(int));
    int*   cursor2 = (int*)carve((long)I * sizeof(int));
    int*   bsum    = (int*)carve(256 * sizeof(int));
    int*   ent1    = (int*)carve(T1 * sizeof(int));
    int2*  ent2    = (int2*)carve((long)S * sizeof(int2));

    const int nb1 = (M + 1023) / 1024;
    const int nb2 = (I + 1023) / 1024;

    // 1) degrees (fused) -> norm
    hipMemsetAsync(deg1, 0, M * sizeof(int), stream);
    hipMemsetAsync(deg2, 0, I * sizeof(int), stream);
    deg_fused_kernel<<<(E + 255) / 256, 256, 0, stream>>>(edge_user, edge_item, E, U,
                                                          s_row, S, deg1, deg2);
    norm_kernel<<<(M + 255) / 256, 256, 0, stream>>>(deg1, norm, M);

    // 2) scans -> rowptr1/cursor1 (bipartite, M rows), rowptr2/cursor2 (s, I rows)
    scan_block<<<nb1, 1024, 0, stream>>>(deg1, incl, bsum, M);
    scan_bsum<<<1, 256, 0, stream>>>(bsum, nb1);
    finalize_rowptr<<<(M + 256) / 256, 256, 0, stream>>>(incl, deg1, bsum,
                                                         rowptr1, cursor1, M);
    scan_block<<<nb2, 1024, 0, stream>>>(deg2, incl, bsum, I);
    scan_bsum<<<1, 256, 0, stream>>>(bsum, nb2);
    finalize_rowptr<<<(I + 256) / 256, 256, 0, stream>>>(incl, deg2, bsum,
                                                         rowptr2, cursor2, I);

    // 3) scatter edges
    scatter_bip<<<(E + 255) / 256, 256, 0, stream>>>(edge_user, edge_item, E, U,
                                                     cursor1, ent1);
    scatter_s<<<(S + 255) / 256, 256, 0, stream>>>(s_row, s_col, s_val, S, U,
                                                   cursor2, ent2);

    // 4) init cur = e0
    init_kernel<<<2048, 256, 0, stream>>>((const float4v*)user_emb, (const float4v*)item_emb,
                                          (long)U * (EMB_D / 4), MD / 4, (float4v*)bufA);

    // 5) L=3 gather layers with deferred output accumulation
    const int gblocks = (int)(((long)M * 64 + 255) / 256);
    gather_kernel<0><<<gblocks, 256, 0, stream>>>(rowptr1, ent1, rowptr2, ent2, norm,
                                                  bufA, bufB, nullptr, U, M);
    gather_kernel<1><<<gblocks, 256, 0, stream>>>(rowptr1, ent1, rowptr2, ent2, norm,
                                                  bufB, bufA, out, U, M);
    gather_kernel<2><<<gblocks, 256, 0, stream>>>(rowptr1, ent1, rowptr2, ent2, norm,
                                                  bufA, nullptr, out, U, M);
}

// Round 5
// 544.494 us; speedup vs baseline: 1.1483x; 1.1483x over previous
//
#include <hip/hip_runtime.h>

#define EMB_D 64
#define NCLS 8   // row-range partitions, aligned to blockIdx % 8 ~ XCD round-robin

typedef float float4v __attribute__((ext_vector_type(4)));

// ---------------------------------------------------------------------------
// partitioned degree kernel: class c handles only destination rows in its
// 1/8 range -> atomics land in a small L2-resident (XCD-local) window.
// deg1: bipartite degrees over M rows. deg2: s-row degrees over I item rows.
// ---------------------------------------------------------------------------
__global__ void deg_part_kernel(const int* __restrict__ eu, const int* __restrict__ ei,
                                int E, int U,
                                const int* __restrict__ sr, int S,
                                int I, int M,
                                int* __restrict__ deg1, int* __restrict__ deg2) {
    int cls = blockIdx.x & (NCLS - 1);
    long e  = ((long)(blockIdx.x >> 3)) * blockDim.x + threadIdx.x;
    int lo1 = (int)((long)cls * M / NCLS), hi1 = (int)((long)(cls + 1) * M / NCLS);
    int lo2 = (int)((long)cls * I / NCLS), hi2 = (int)((long)(cls + 1) * I / NCLS);
    if (e < E) {
        int u  = eu[e];
        int iv = U + ei[e];
        if (u  >= lo1 && u  < hi1) atomicAdd(&deg1[u], 1);
        if (iv >= lo1 && iv < hi1) atomicAdd(&deg1[iv], 1);
    }
    if (e < S) {
        int r = sr[e];
        if (r >= lo2 && r < hi2) atomicAdd(&deg2[r], 1);
    }
}

// norm[m] = rsqrt(deg1[m] + 1)
__global__ void norm_kernel(const int* __restrict__ deg, float* __restrict__ norm, int M) {
    int m = blockIdx.x * blockDim.x + threadIdx.x;
    if (m < M) norm[m] = rsqrtf((float)deg[m] + 1.0f);
}

// ---------------------------------------------------------------------------
// 3-kernel exclusive scan of deg[n] -> rowptr[n+1], cursor[n]
// ---------------------------------------------------------------------------
__global__ void __launch_bounds__(1024) scan_block(const int* __restrict__ deg,
                                                   int* __restrict__ incl,
                                                   int* __restrict__ bsum, int n) {
    __shared__ int sh[1024];
    int i = blockIdx.x * 1024 + threadIdx.x;
    int v = (i < n) ? deg[i] : 0;
    sh[threadIdx.x] = v;
    __syncthreads();
    for (int ofs = 1; ofs < 1024; ofs <<= 1) {
        int t = (threadIdx.x >= ofs) ? sh[threadIdx.x - ofs] : 0;
        __syncthreads();
        sh[threadIdx.x] += t;
        __syncthreads();
    }
    if (i < n) incl[i] = sh[threadIdx.x];
    if (threadIdx.x == 1023) bsum[blockIdx.x] = sh[1023];
}

__global__ void __launch_bounds__(256) scan_bsum(int* __restrict__ bsum, int nb) {
    __shared__ int sh[256];
    int v = (threadIdx.x < nb) ? bsum[threadIdx.x] : 0;
    sh[threadIdx.x] = v;
    __syncthreads();
    for (int ofs = 1; ofs < 256; ofs <<= 1) {
        int t = (threadIdx.x >= ofs) ? sh[threadIdx.x - ofs] : 0;
        __syncthreads();
        sh[threadIdx.x] += t;
        __syncthreads();
    }
    if (threadIdx.x < nb) bsum[threadIdx.x] = sh[threadIdx.x] - v;  // exclusive
}

__global__ void finalize_rowptr(const int* __restrict__ incl, const int* __restrict__ deg,
                                const int* __restrict__ bsum, int* __restrict__ rowptr,
                                int* __restrict__ cursor, int n) {
    int i = blockIdx.x * blockDim.x + threadIdx.x;
    if (i < n) {
        int v = incl[i] - deg[i] + bsum[i >> 10];
        rowptr[i] = v;
        cursor[i] = v;
    } else if (i == n) {
        rowptr[n] = incl[n - 1] + bsum[(n - 1) >> 10];
    }
}

// ---------------------------------------------------------------------------
// partitioned bipartite scatter: class c writes only rows in its 1/8 range.
// CSR write window per class ~1MB, cursor window ~75KB -> L2-resident.
// ---------------------------------------------------------------------------
__global__ void scatter_bip_part(const int* __restrict__ eu, const int* __restrict__ ei,
                                 int E, int U, int M,
                                 int* __restrict__ cursor1, int* __restrict__ col1) {
    int cls = blockIdx.x & (NCLS - 1);
    long e  = ((long)(blockIdx.x >> 3)) * blockDim.x + threadIdx.x;
    if (e >= E) return;
    int lo = (int)((long)cls * M / NCLS), hi = (int)((long)(cls + 1) * M / NCLS);
    int u  = eu[e];
    int iv = U + ei[e];
    if (u >= lo && u < hi) {
        int p = atomicAdd(&cursor1[u], 1);
        col1[p] = iv;
    }
    if (iv >= lo && iv < hi) {
        int p = atomicAdd(&cursor1[iv], 1);
        col1[p] = u;
    }
}

// partitioned s-edge scatter: packed (col, w_bits), item-row indexed
__global__ void scatter_s_part(const int* __restrict__ sr, const int* __restrict__ sc,
                               const float* __restrict__ sv, int S, int U, int I,
                               int* __restrict__ cursor2, int2* __restrict__ ent2) {
    int cls = blockIdx.x & (NCLS - 1);
    long e  = ((long)(blockIdx.x >> 3)) * blockDim.x + threadIdx.x;
    if (e >= S) return;
    int lo = (int)((long)cls * I / NCLS), hi = (int)((long)(cls + 1) * I / NCLS);
    int r = sr[e];
    if (r >= lo && r < hi) {
        int p = atomicAdd(&cursor2[r], 1);
        ent2[p] = make_int2(U + sc[e], __float_as_int(sv[e]));
    }
}

// ---------------------------------------------------------------------------
// cur = concat(user_emb, item_emb)   (float4)
// ---------------------------------------------------------------------------
__global__ void init_kernel(const float4v* __restrict__ ue, const float4v* __restrict__ ie,
                            long u4, long total4, float4v* __restrict__ cur) {
    long stride = (long)gridDim.x * blockDim.x;
    for (long idx = (long)blockIdx.x * blockDim.x + threadIdx.x; idx < total4; idx += stride) {
        cur[idx] = (idx < u4) ? ue[idx] : ie[idx - u4];
    }
}

// ---------------------------------------------------------------------------
// gather: one wave per destination node; 4 edge-groups x 16 lanes x float4.
// Bipartite weights recomputed as norm[dst]*norm[col].
// MODE 0: nxt = acc                       (layer 1: e0->e1)
// MODE 1: a0=nxt[o]; b1=cur[o]; nxt=acc; out=a0+b1+acc   (layer 2: partial sum)
// MODE 2: out = 0.25*(out + acc)         (layer 3: final average)
// ---------------------------------------------------------------------------
template <int MODE>
__global__ void __launch_bounds__(256) gather_kernel(const int* __restrict__ rp1,
                                                     const int* __restrict__ ent1,
                                                     const int* __restrict__ rp2,
                                                     const int2* __restrict__ ent2,
                                                     const float* __restrict__ norm,
                                                     const float* __restrict__ cur,
                                                     float* __restrict__ nxt,
                                                     float* __restrict__ out,
                                                     int U, int M) {
    int wid  = (int)((blockIdx.x * (long)blockDim.x + threadIdx.x) >> 6);
    int lane = threadIdx.x & 63;
    int g    = lane >> 4;       // edge group 0..3
    int l    = lane & 15;       // float4 slot within row
    if (wid >= M) return;
    float nd = norm[wid];
    int beg = rp1[wid];
    int end = rp1[wid + 1];

    float4v acc = {0.f, 0.f, 0.f, 0.f};
    int j = beg + g;
    if (j < end) {
        int c0 = ent1[j];
        float4v v0 = ((const float4v*)(cur + (long)c0 * EMB_D))[l];
        float  n0 = norm[c0];
        for (j += 4; j < end; j += 4) {
            int c1 = ent1[j];
            float4v v1 = ((const float4v*)(cur + (long)c1 * EMB_D))[l];
            float  n1 = norm[c1];
            acc += (nd * n0) * v0;
            v0 = v1; n0 = n1;
        }
        acc += (nd * n0) * v0;
    }

    if (wid >= U) {   // item rows also receive s-edges
        int r = wid - U;
        int b2 = rp2[r];
        int e2 = rp2[r + 1];
        j = b2 + g;
        if (j < e2) {
            int2 E0 = ent2[j];
            float4v v0 = ((const float4v*)(cur + (long)E0.x * EMB_D))[l];
            float  w0 = __int_as_float(E0.y);
            for (j += 4; j < e2; j += 4) {
                int2 E1 = ent2[j];
                float4v v1 = ((const float4v*)(cur + (long)E1.x * EMB_D))[l];
                float  w1 = __int_as_float(E1.y);
                acc += w0 * v0;
                v0 = v1; w0 = w1;
            }
            acc += w0 * v0;
        }
    }

    // reduce across the 4 groups
    acc.x += __shfl_xor(acc.x, 16); acc.y += __shfl_xor(acc.y, 16);
    acc.z += __shfl_xor(acc.z, 16); acc.w += __shfl_xor(acc.w, 16);
    acc.x += __shfl_xor(acc.x, 32); acc.y += __shfl_xor(acc.y, 32);
    acc.z += __shfl_xor(acc.z, 32); acc.w += __shfl_xor(acc.w, 32);

    if (g == 0) {
        long o4 = (long)wid * 16 + l;
        if (MODE == 0) {
            ((float4v*)nxt)[o4] = acc;
        } else if (MODE == 1) {
            float4v a0 = ((const float4v*)nxt)[o4];   // e0 (own row, pre-overwrite)
            float4v b1 = ((const float4v*)cur)[o4];   // e1 (own row of cur)
            ((float4v*)nxt)[o4] = acc;                // e2 for next layer's cur
            ((float4v*)out)[o4] = a0 + b1 + acc;      // partial sum e0+e1+e2
        } else {
            float4v p = ((const float4v*)out)[o4];
            ((float4v*)out)[o4] = 0.25f * (p + acc);
        }
    }
}

extern "C" void kernel_launch(void* const* d_in, const int* in_sizes, int n_in,
                              void* d_out, int out_size, void* d_ws, size_t ws_size,
                              hipStream_t stream) {
    const float* user_emb = (const float*)d_in[0];
    const float* item_emb = (const float*)d_in[1];
    const int*   edge_user = (const int*)d_in[2];
    const int*   edge_item = (const int*)d_in[3];
    const int*   s_row = (const int*)d_in[4];
    const int*   s_col = (const int*)d_in[5];
    const float* s_val = (const float*)d_in[6];
    float* out = (float*)d_out;

    const int U = in_sizes[0] / EMB_D;
    const int I = in_sizes[1] / EMB_D;
    const int M = U + I;
    const int E = in_sizes[2];
    const int S = in_sizes[4];
    const long MD = (long)M * EMB_D;
    const long T1 = 2L * E;           // bipartite CSR entries

    // workspace carve-up, 16B-aligned chunks
    char* p = (char*)d_ws;
    auto carve = [&](long bytes) {
        char* q = p;
        p += (bytes + 15) & ~15L;
        return q;
    };
    float* bufA    = (float*)carve(MD * sizeof(float));
    float* bufB    = (float*)carve(MD * sizeof(float));
    float* norm    = (float*)carve((long)M * sizeof(float));
    int*   deg1    = (int*)carve((long)M * sizeof(int));
    int*   deg2    = (int*)carve((long)I * sizeof(int));
    int*   incl    = (int*)carve((long)M * sizeof(int));
    int*   rowptr1 = (int*)carve((long)(M + 1) * sizeof(int));
    int*   cursor1 = (int*)carve((long)M * sizeof(int));
    int*   rowptr2 = (int*)carve((long)(I + 1) * sizeof(int));
    int*   cursor2 = (int*)carve((long)I * sizeof(int));
    int*   bsum    = (int*)carve(256 * sizeof(int));
    int*   ent1    = (int*)carve(T1 * sizeof(int));
    int2*  ent2    = (int2*)carve((long)S * sizeof(int2));

    const int nb1 = (M + 1023) / 1024;
    const int nb2 = (I + 1023) / 1024;
    const int nbE = (E + 255) / 256;          // per-class blocks for E-sized loops
    const int nbS = (S + 255) / 256;

    // 1) partitioned degrees -> norm
    hipMemsetAsync(deg1, 0, M * sizeof(int), stream);
    hipMemsetAsync(deg2, 0, I * sizeof(int), stream);
    deg_part_kernel<<<NCLS * nbE, 256, 0, stream>>>(edge_user, edge_item, E, U,
                                                    s_row, S, I, M, deg1, deg2);
    norm_kernel<<<(M + 255) / 256, 256, 0, stream>>>(deg1, norm, M);

    // 2) scans -> rowptr1/cursor1 (bipartite, M rows), rowptr2/cursor2 (s, I rows)
    scan_block<<<nb1, 1024, 0, stream>>>(deg1, incl, bsum, M);
    scan_bsum<<<1, 256, 0, stream>>>(bsum, nb1);
    finalize_rowptr<<<(M + 256) / 256, 256, 0, stream>>>(incl, deg1, bsum,
                                                         rowptr1, cursor1, M);
    scan_block<<<nb2, 1024, 0, stream>>>(deg2, incl, bsum, I);
    scan_bsum<<<1, 256, 0, stream>>>(bsum, nb2);
    finalize_rowptr<<<(I + 256) / 256, 256, 0, stream>>>(incl, deg2, bsum,
                                                         rowptr2, cursor2, I);

    // 3) partitioned scatters (row-range windows keep writes L2-local)
    scatter_bip_part<<<NCLS * nbE, 256, 0, stream>>>(edge_user, edge_item, E, U, M,
                                                     cursor1, ent1);
    scatter_s_part<<<NCLS * nbS, 256, 0, stream>>>(s_row, s_col, s_val, S, U, I,
                                                   cursor2, ent2);

    // 4) init cur = e0
    init_kernel<<<2048, 256, 0, stream>>>((const float4v*)user_emb, (const float4v*)item_emb,
                                          (long)U * (EMB_D / 4), MD / 4, (float4v*)bufA);

    // 5) L=3 gather layers with deferred output accumulation
    const int gblocks = (int)(((long)M * 64 + 255) / 256);
    gather_kernel<0><<<gblocks, 256, 0, stream>>>(rowptr1, ent1, rowptr2, ent2, norm,
                                                  bufA, bufB, nullptr, U, M);
    gather_kernel<1><<<gblocks, 256, 0, stream>>>(rowptr1, ent1, rowptr2, ent2, norm,
                                                  bufB, bufA, out, U, M);
    gather_kernel<2><<<gblocks, 256, 0, stream>>>(rowptr1, ent1, rowptr2, ent2, norm,
                                                  bufA, nullptr, out, U, M);
}

// Round 6
// 528.963 us; speedup vs baseline: 1.1820x; 1.0294x over previous
//
#include <hip/hip_runtime.h>

#define EMB_D 64
#define NCLS 8   // row-range partitions, aligned to blockIdx % 8 ~ XCD round-robin

typedef float    float4v __attribute__((ext_vector_type(4)));
typedef _Float16 half4v  __attribute__((ext_vector_type(4)));

// ---------------------------------------------------------------------------
// partitioned degree kernel: class c handles only destination rows in its
// 1/8 range -> atomics land in a small L2-resident window.
// ---------------------------------------------------------------------------
__global__ void deg_part_kernel(const int* __restrict__ eu, const int* __restrict__ ei,
                                int E, int U,
                                const int* __restrict__ sr, int S,
                                int I, int M,
                                int* __restrict__ deg1, int* __restrict__ deg2) {
    int cls = blockIdx.x & (NCLS - 1);
    long e  = ((long)(blockIdx.x >> 3)) * blockDim.x + threadIdx.x;
    int lo1 = (int)((long)cls * M / NCLS), hi1 = (int)((long)(cls + 1) * M / NCLS);
    int lo2 = (int)((long)cls * I / NCLS), hi2 = (int)((long)(cls + 1) * I / NCLS);
    if (e < E) {
        int u  = eu[e];
        int iv = U + ei[e];
        if (u  >= lo1 && u  < hi1) atomicAdd(&deg1[u], 1);
        if (iv >= lo1 && iv < hi1) atomicAdd(&deg1[iv], 1);
    }
    if (e < S) {
        int r = sr[e];
        if (r >= lo2 && r < hi2) atomicAdd(&deg2[r], 1);
    }
}

// norm[m] = rsqrt(deg1[m] + 1)
__global__ void norm_kernel(const int* __restrict__ deg, float* __restrict__ norm, int M) {
    int m = blockIdx.x * blockDim.x + threadIdx.x;
    if (m < M) norm[m] = rsqrtf((float)deg[m] + 1.0f);
}

// ---------------------------------------------------------------------------
// 3-kernel exclusive scan of deg[n] -> rowptr[n+1], cursor[n]
// ---------------------------------------------------------------------------
__global__ void __launch_bounds__(1024) scan_block(const int* __restrict__ deg,
                                                   int* __restrict__ incl,
                                                   int* __restrict__ bsum, int n) {
    __shared__ int sh[1024];
    int i = blockIdx.x * 1024 + threadIdx.x;
    int v = (i < n) ? deg[i] : 0;
    sh[threadIdx.x] = v;
    __syncthreads();
    for (int ofs = 1; ofs < 1024; ofs <<= 1) {
        int t = (threadIdx.x >= ofs) ? sh[threadIdx.x - ofs] : 0;
        __syncthreads();
        sh[threadIdx.x] += t;
        __syncthreads();
    }
    if (i < n) incl[i] = sh[threadIdx.x];
    if (threadIdx.x == 1023) bsum[blockIdx.x] = sh[1023];
}

__global__ void __launch_bounds__(256) scan_bsum(int* __restrict__ bsum, int nb) {
    __shared__ int sh[256];
    int v = (threadIdx.x < nb) ? bsum[threadIdx.x] : 0;
    sh[threadIdx.x] = v;
    __syncthreads();
    for (int ofs = 1; ofs < 256; ofs <<= 1) {
        int t = (threadIdx.x >= ofs) ? sh[threadIdx.x - ofs] : 0;
        __syncthreads();
        sh[threadIdx.x] += t;
        __syncthreads();
    }
    if (threadIdx.x < nb) bsum[threadIdx.x] = sh[threadIdx.x] - v;  // exclusive
}

__global__ void finalize_rowptr(const int* __restrict__ incl, const int* __restrict__ deg,
                                const int* __restrict__ bsum, int* __restrict__ rowptr,
                                int* __restrict__ cursor, int n) {
    int i = blockIdx.x * blockDim.x + threadIdx.x;
    if (i < n) {
        int v = incl[i] - deg[i] + bsum[i >> 10];
        rowptr[i] = v;
        cursor[i] = v;
    } else if (i == n) {
        rowptr[n] = incl[n - 1] + bsum[(n - 1) >> 10];
    }
}

// ---------------------------------------------------------------------------
// partitioned bipartite scatter: class c writes only rows in its 1/8 range.
// ---------------------------------------------------------------------------
__global__ void scatter_bip_part(const int* __restrict__ eu, const int* __restrict__ ei,
                                 int E, int U, int M,
                                 int* __restrict__ cursor1, int* __restrict__ col1) {
    int cls = blockIdx.x & (NCLS - 1);
    long e  = ((long)(blockIdx.x >> 3)) * blockDim.x + threadIdx.x;
    if (e >= E) return;
    int lo = (int)((long)cls * M / NCLS), hi = (int)((long)(cls + 1) * M / NCLS);
    int u  = eu[e];
    int iv = U + ei[e];
    if (u >= lo && u < hi) {
        int p = atomicAdd(&cursor1[u], 1);
        col1[p] = iv;
    }
    if (iv >= lo && iv < hi) {
        int p = atomicAdd(&cursor1[iv], 1);
        col1[p] = u;
    }
}

// partitioned s-edge scatter: packed (col, w_bits), item-row indexed
__global__ void scatter_s_part(const int* __restrict__ sr, const int* __restrict__ sc,
                               const float* __restrict__ sv, int S, int U, int I,
                               int* __restrict__ cursor2, int2* __restrict__ ent2) {
    int cls = blockIdx.x & (NCLS - 1);
    long e  = ((long)(blockIdx.x >> 3)) * blockDim.x + threadIdx.x;
    if (e >= S) return;
    int lo = (int)((long)cls * I / NCLS), hi = (int)((long)(cls + 1) * I / NCLS);
    int r = sr[e];
    if (r >= lo && r < hi) {
        int p = atomicAdd(&cursor2[r], 1);
        ent2[p] = make_int2(U + sc[e], __float_as_int(sv[e]));
    }
}

// ---------------------------------------------------------------------------
// cur0 (fp16) = concat(user_emb, item_emb)
// ---------------------------------------------------------------------------
__global__ void init_kernel(const float4v* __restrict__ ue, const float4v* __restrict__ ie,
                            long u4, long total4, half4v* __restrict__ curH) {
    long stride = (long)gridDim.x * blockDim.x;
    for (long idx = (long)blockIdx.x * blockDim.x + threadIdx.x; idx < total4; idx += stride) {
        float4v v = (idx < u4) ? ue[idx] : ie[idx - u4];
        curH[idx] = __builtin_convertvector(v, half4v);
    }
}

// ---------------------------------------------------------------------------
// gather: one wave per destination node; 4 edge-groups x 16 lanes.
// Heavy-first scheduling: item rows (long, with s-edges) dispatched first.
// MODE 0: read fp16 curH  -> write fp16 dstH           (e0 -> e1)
// MODE 1: read fp16 curH  -> write fp32 dstF (=e2) and out = e0+e1+e2
//         (e0/e1 own-row terms read from the fp16 copies)
// MODE 2: read fp32 curF  -> out = 0.25*(out + e3)
// ---------------------------------------------------------------------------
template <int MODE>
__global__ void __launch_bounds__(256) gather_kernel(const int* __restrict__ rp1,
                                                     const int* __restrict__ ent1,
                                                     const int* __restrict__ rp2,
                                                     const int2* __restrict__ ent2,
                                                     const float* __restrict__ norm,
                                                     const _Float16* __restrict__ curH,
                                                     const float* __restrict__ curF,
                                                     const _Float16* __restrict__ cur0H,
                                                     _Float16* __restrict__ dstH,
                                                     float* __restrict__ dstF,
                                                     float* __restrict__ out,
                                                     int U, int I, int M) {
    int raw  = (int)((blockIdx.x * (long)blockDim.x + threadIdx.x) >> 6);
    int lane = threadIdx.x & 63;
    int g    = lane >> 4;       // edge group 0..3
    int l    = lane & 15;       // 4-dim slot within row
    if (raw >= M) return;
    // heavy-first: items (rows U..M-1) first, users fill the tail
    int row = (raw < I) ? (U + raw) : (raw - I);
    float nd = norm[row];
    int beg = rp1[row];
    int end = rp1[row + 1];

    float4v acc = {0.f, 0.f, 0.f, 0.f};
    int j = beg + g;
    if (j < end) {
        int c0 = ent1[j];
        float4v v0;
        if (MODE == 2) v0 = ((const float4v*)(curF + (long)c0 * EMB_D))[l];
        else           v0 = __builtin_convertvector(((const half4v*)(curH + (long)c0 * EMB_D))[l], float4v);
        float n0 = norm[c0];
        for (j += 4; j < end; j += 4) {
            int c1 = ent1[j];
            float4v v1;
            if (MODE == 2) v1 = ((const float4v*)(curF + (long)c1 * EMB_D))[l];
            else           v1 = __builtin_convertvector(((const half4v*)(curH + (long)c1 * EMB_D))[l], float4v);
            float n1 = norm[c1];
            acc += (nd * n0) * v0;
            v0 = v1; n0 = n1;
        }
        acc += (nd * n0) * v0;
    }

    if (row >= U) {   // item rows also receive s-edges
        int r = row - U;
        int b2 = rp2[r];
        int e2 = rp2[r + 1];
        j = b2 + g;
        if (j < e2) {
            int2 E0 = ent2[j];
            float4v v0;
            if (MODE == 2) v0 = ((const float4v*)(curF + (long)E0.x * EMB_D))[l];
            else           v0 = __builtin_convertvector(((const half4v*)(curH + (long)E0.x * EMB_D))[l], float4v);
            float w0 = __int_as_float(E0.y);
            for (j += 4; j < e2; j += 4) {
                int2 E1 = ent2[j];
                float4v v1;
                if (MODE == 2) v1 = ((const float4v*)(curF + (long)E1.x * EMB_D))[l];
                else           v1 = __builtin_convertvector(((const half4v*)(curH + (long)E1.x * EMB_D))[l], float4v);
                float w1 = __int_as_float(E1.y);
                acc += w0 * v0;
                v0 = v1; w0 = w1;
            }
            acc += w0 * v0;
        }
    }

    // reduce across the 4 groups
    acc.x += __shfl_xor(acc.x, 16); acc.y += __shfl_xor(acc.y, 16);
    acc.z += __shfl_xor(acc.z, 16); acc.w += __shfl_xor(acc.w, 16);
    acc.x += __shfl_xor(acc.x, 32); acc.y += __shfl_xor(acc.y, 32);
    acc.z += __shfl_xor(acc.z, 32); acc.w += __shfl_xor(acc.w, 32);

    if (g == 0) {
        long o4 = (long)row * 16 + l;
        if (MODE == 0) {
            ((half4v*)dstH)[o4] = __builtin_convertvector(acc, half4v);
        } else if (MODE == 1) {
            float4v a0 = __builtin_convertvector(((const half4v*)cur0H)[o4], float4v); // e0
            float4v b1 = __builtin_convertvector(((const half4v*)curH)[o4], float4v);  // e1
            ((float4v*)dstF)[o4] = acc;                 // e2 (fp32) for layer 3
            ((float4v*)out)[o4]  = a0 + b1 + acc;       // partial sum e0+e1+e2
        } else {
            float4v p = ((const float4v*)out)[o4];
            ((float4v*)out)[o4] = 0.25f * (p + acc);
        }
    }
}

extern "C" void kernel_launch(void* const* d_in, const int* in_sizes, int n_in,
                              void* d_out, int out_size, void* d_ws, size_t ws_size,
                              hipStream_t stream) {
    const float* user_emb = (const float*)d_in[0];
    const float* item_emb = (const float*)d_in[1];
    const int*   edge_user = (const int*)d_in[2];
    const int*   edge_item = (const int*)d_in[3];
    const int*   s_row = (const int*)d_in[4];
    const int*   s_col = (const int*)d_in[5];
    const float* s_val = (const float*)d_in[6];
    float* out = (float*)d_out;

    const int U = in_sizes[0] / EMB_D;
    const int I = in_sizes[1] / EMB_D;
    const int M = U + I;
    const int E = in_sizes[2];
    const int S = in_sizes[4];
    const long MD = (long)M * EMB_D;
    const long T1 = 2L * E;           // bipartite CSR entries

    // workspace carve-up, 16B-aligned chunks
    char* p = (char*)d_ws;
    auto carve = [&](long bytes) {
        char* q = p;
        p += (bytes + 15) & ~15L;
        return q;
    };
    _Float16* cur0H  = (_Float16*)carve(MD * sizeof(_Float16));  // e0 (fp16)
    _Float16* cur1H  = (_Float16*)carve(MD * sizeof(_Float16));  // e1 (fp16)
    float*    bufC   = (float*)carve(MD * sizeof(float));        // e2 (fp32)
    float*    norm   = (float*)carve((long)M * sizeof(float));
    int*   deg1    = (int*)carve((long)M * sizeof(int));
    int*   deg2    = (int*)carve((long)I * sizeof(int));
    int*   incl    = (int*)carve((long)M * sizeof(int));
    int*   rowptr1 = (int*)carve((long)(M + 1) * sizeof(int));
    int*   cursor1 = (int*)carve((long)M * sizeof(int));
    int*   rowptr2 = (int*)carve((long)(I + 1) * sizeof(int));
    int*   cursor2 = (int*)carve((long)I * sizeof(int));
    int*   bsum    = (int*)carve(256 * sizeof(int));
    int*   ent1    = (int*)carve(T1 * sizeof(int));
    int2*  ent2    = (int2*)carve((long)S * sizeof(int2));

    const int nb1 = (M + 1023) / 1024;
    const int nb2 = (I + 1023) / 1024;
    const int nbE = (E + 255) / 256;
    const int nbS = (S + 255) / 256;

    // 1) partitioned degrees -> norm
    hipMemsetAsync(deg1, 0, M * sizeof(int), stream);
    hipMemsetAsync(deg2, 0, I * sizeof(int), stream);
    deg_part_kernel<<<NCLS * nbE, 256, 0, stream>>>(edge_user, edge_item, E, U,
                                                    s_row, S, I, M, deg1, deg2);
    norm_kernel<<<(M + 255) / 256, 256, 0, stream>>>(deg1, norm, M);

    // 2) scans -> rowptr1/cursor1 (bipartite, M rows), rowptr2/cursor2 (s, I rows)
    scan_block<<<nb1, 1024, 0, stream>>>(deg1, incl, bsum, M);
    scan_bsum<<<1, 256, 0, stream>>>(bsum, nb1);
    finalize_rowptr<<<(M + 256) / 256, 256, 0, stream>>>(incl, deg1, bsum,
                                                         rowptr1, cursor1, M);
    scan_block<<<nb2, 1024, 0, stream>>>(deg2, incl, bsum, I);
    scan_bsum<<<1, 256, 0, stream>>>(bsum, nb2);
    finalize_rowptr<<<(I + 256) / 256, 256, 0, stream>>>(incl, deg2, bsum,
                                                         rowptr2, cursor2, I);

    // 3) partitioned scatters (row-range windows keep writes L2-local)
    scatter_bip_part<<<NCLS * nbE, 256, 0, stream>>>(edge_user, edge_item, E, U, M,
                                                     cursor1, ent1);
    scatter_s_part<<<NCLS * nbS, 256, 0, stream>>>(s_row, s_col, s_val, S, U, I,
                                                   cursor2, ent2);

    // 4) init cur0 (fp16)
    init_kernel<<<2048, 256, 0, stream>>>((const float4v*)user_emb, (const float4v*)item_emb,
                                          (long)U * (EMB_D / 4), MD / 4, (half4v*)cur0H);

    // 5) L=3 gather layers: fp16 reads for layers 1-2, fp32 for layer 3
    const int gblocks = (int)(((long)M * 64 + 255) / 256);
    gather_kernel<0><<<gblocks, 256, 0, stream>>>(rowptr1, ent1, rowptr2, ent2, norm,
                                                  cur0H, nullptr, nullptr,
                                                  cur1H, nullptr, nullptr, U, I, M);
    gather_kernel<1><<<gblocks, 256, 0, stream>>>(rowptr1, ent1, rowptr2, ent2, norm,
                                                  cur1H, nullptr, cur0H,
                                                  nullptr, bufC, out, U, I, M);
    gather_kernel<2><<<gblocks, 256, 0, stream>>>(rowptr1, ent1, rowptr2, ent2, norm,
                                                  nullptr, bufC, nullptr,
                                                  nullptr, nullptr, out, U, I, M);
}

// Round 7
// 462.566 us; speedup vs baseline: 1.3516x; 1.1435x over previous
//
#include <hip/hip_runtime.h>
#include <type_traits>

#define EMB_D 64
#define NCLS 8   // row-range partitions, aligned to blockIdx % 8 ~ XCD round-robin

typedef float    float4v __attribute__((ext_vector_type(4)));
typedef _Float16 half4v  __attribute__((ext_vector_type(4)));

__device__ inline float4v tof32(half4v v)  { return __builtin_convertvector(v, float4v); }
__device__ inline float4v tof32(float4v v) { return v; }

// ---------------------------------------------------------------------------
// fused partitioned degree kernel: bip degrees (deg, both dirs) + s-row
// degrees (degs). Class c only touches dst rows in its 1/8 of [0,M).
// ---------------------------------------------------------------------------
__global__ void deg_part_kernel(const int* __restrict__ eu, const int* __restrict__ ei,
                                int E, int U,
                                const int* __restrict__ sr, int S, int M,
                                int* __restrict__ deg, int* __restrict__ degs) {
    int cls = blockIdx.x & (NCLS - 1);
    long e  = ((long)(blockIdx.x >> 3)) * blockDim.x + threadIdx.x;
    int lo = (int)((long)cls * M / NCLS), hi = (int)((long)(cls + 1) * M / NCLS);
    if (e < E) {
        int u  = eu[e];
        int iv = U + ei[e];
        if (u  >= lo && u  < hi) atomicAdd(&deg[u], 1);
        if (iv >= lo && iv < hi) atomicAdd(&deg[iv], 1);
    }
    if (e < S) {
        int r = sr[e];
        int dst = U + r;
        if (dst >= lo && dst < hi) atomicAdd(&degs[r], 1);
    }
}

// ---------------------------------------------------------------------------
// scan phase 1 over combined row lengths len[i] = deg[i] + (i>=U ? degs : 0);
// also emits norm[i] = rsqrt(deg[i]+1) for free (deg already being read).
// ---------------------------------------------------------------------------
__global__ void __launch_bounds__(1024) scan_block(const int* __restrict__ deg,
                                                   const int* __restrict__ degs,
                                                   int U, int n,
                                                   float* __restrict__ norm,
                                                   int* __restrict__ incl,
                                                   int* __restrict__ bsum) {
    __shared__ int sh[1024];
    int i = blockIdx.x * 1024 + threadIdx.x;
    int d = (i < n) ? deg[i] : 0;
    int v = d;
    if (i < n && i >= U) v += degs[i - U];
    if (i < n) norm[i] = rsqrtf((float)d + 1.0f);
    sh[threadIdx.x] = v;
    __syncthreads();
    for (int ofs = 1; ofs < 1024; ofs <<= 1) {
        int t = (threadIdx.x >= ofs) ? sh[threadIdx.x - ofs] : 0;
        __syncthreads();
        sh[threadIdx.x] += t;
        __syncthreads();
    }
    if (i < n) incl[i] = sh[threadIdx.x];
    if (threadIdx.x == 1023) bsum[blockIdx.x] = sh[1023];
}

__global__ void __launch_bounds__(256) scan_bsum(int* __restrict__ bsum, int nb) {
    __shared__ int sh[256];
    int v = (threadIdx.x < nb) ? bsum[threadIdx.x] : 0;
    sh[threadIdx.x] = v;
    __syncthreads();
    for (int ofs = 1; ofs < 256; ofs <<= 1) {
        int t = (threadIdx.x >= ofs) ? sh[threadIdx.x - ofs] : 0;
        __syncthreads();
        sh[threadIdx.x] += t;
        __syncthreads();
    }
    if (threadIdx.x < nb) bsum[threadIdx.x] = sh[threadIdx.x] - v;  // exclusive
}

__global__ void finalize_rowptr(const int* __restrict__ incl, const int* __restrict__ deg,
                                const int* __restrict__ degs,
                                const int* __restrict__ bsum, int U, int n,
                                int* __restrict__ rowptr, int* __restrict__ cursor) {
    int i = blockIdx.x * blockDim.x + threadIdx.x;
    if (i < n) {
        int len = deg[i] + (i >= U ? degs[i - U] : 0);
        int v = incl[i] - len + bsum[i >> 10];
        rowptr[i] = v;
        cursor[i] = v;
    } else if (i == n) {
        rowptr[n] = incl[n - 1] + bsum[(n - 1) >> 10];
    }
}

// ---------------------------------------------------------------------------
// merged partitioned scatter: bip edges (both dirs, w=norm*norm) and s-edges
// into ONE (col, w_bits) CSR. Class c writes only rows in its 1/8 window.
// ---------------------------------------------------------------------------
__global__ void scatter_all(const int* __restrict__ eu, const int* __restrict__ ei,
                            int E, int nbE,
                            const int* __restrict__ sr, const int* __restrict__ sc,
                            const float* __restrict__ sv, int S,
                            int U, int M, const float* __restrict__ norm,
                            int* __restrict__ cursor, int2* __restrict__ ent) {
    int cls = blockIdx.x & (NCLS - 1);
    int blk = blockIdx.x >> 3;
    int lo = (int)((long)cls * M / NCLS), hi = (int)((long)(cls + 1) * M / NCLS);
    if (blk < nbE) {
        int e = blk * blockDim.x + threadIdx.x;
        if (e < E) {
            int u  = eu[e];
            int iv = U + ei[e];
            float w = norm[u] * norm[iv];
            int wb = __float_as_int(w);
            if (u >= lo && u < hi) {
                int p = atomicAdd(&cursor[u], 1);
                ent[p] = make_int2(iv, wb);
            }
            if (iv >= lo && iv < hi) {
                int p = atomicAdd(&cursor[iv], 1);
                ent[p] = make_int2(u, wb);
            }
        }
    } else {
        int e = (blk - nbE) * blockDim.x + threadIdx.x;
        if (e < S) {
            int dst = U + sr[e];
            if (dst >= lo && dst < hi) {
                int p = atomicAdd(&cursor[dst], 1);
                ent[p] = make_int2(U + sc[e], __float_as_int(sv[e]));
            }
        }
    }
}

// ---------------------------------------------------------------------------
// cur0 (fp16) = concat(user_emb, item_emb)
// ---------------------------------------------------------------------------
__global__ void init_kernel(const float4v* __restrict__ ue, const float4v* __restrict__ ie,
                            long u4, long total4, half4v* __restrict__ curH) {
    long stride = (long)gridDim.x * blockDim.x;
    for (long idx = (long)blockIdx.x * blockDim.x + threadIdx.x; idx < total4; idx += stride) {
        float4v v = (idx < u4) ? ue[idx] : ie[idx - u4];
        curH[idx] = __builtin_convertvector(v, half4v);
    }
}

// ---------------------------------------------------------------------------
// gather: ONE 16-lane quarter-wave per destination row (4 rows per wave),
// walking the single merged CSR with a 4-deep masked software pipeline
// (invalid slots: w=0, col=0) -> 16 outstanding row loads per wave.
// Heavy-first: item rows dispatched first, users fill the tail.
// MODE 0: read fp16 curH -> write fp16 dstH          (e0 -> e1)
// MODE 1: read fp16 curH -> dstF=e2 (fp32), out = e0+e1+e2
// MODE 2: read fp32 curF -> out = 0.25*(out + e3)
// ---------------------------------------------------------------------------
template <int MODE>
__global__ void __launch_bounds__(256) gather_kernel(const int* __restrict__ rowptr,
                                                     const int2* __restrict__ ent,
                                                     const _Float16* __restrict__ curH,
                                                     const float* __restrict__ curF,
                                                     const _Float16* __restrict__ cur0H,
                                                     _Float16* __restrict__ dstH,
                                                     float* __restrict__ dstF,
                                                     float* __restrict__ out,
                                                     int U, int I, int M) {
    using VecT = typename std::conditional<MODE == 2, float4v, half4v>::type;
    int raw = (int)((((long)blockIdx.x * blockDim.x) + threadIdx.x) >> 4);
    int l   = threadIdx.x & 15;
    if (raw >= M) return;
    int row = (raw < I) ? (U + raw) : (raw - I);
    int beg = rowptr[row];
    int end = rowptr[row + 1];
    const VecT* curv = (MODE == 2) ? (const VecT*)(const void*)curF
                                   : (const VecT*)(const void*)curH;

    float4v acc = {0.f, 0.f, 0.f, 0.f};
    int j = beg;
    int2 a0 = (j + 0 < end) ? ent[j + 0] : make_int2(0, 0);
    int2 a1 = (j + 1 < end) ? ent[j + 1] : make_int2(0, 0);
    int2 a2 = (j + 2 < end) ? ent[j + 2] : make_int2(0, 0);
    int2 a3 = (j + 3 < end) ? ent[j + 3] : make_int2(0, 0);
    VecT v0 = curv[(long)a0.x * 16 + l];
    VecT v1 = curv[(long)a1.x * 16 + l];
    VecT v2 = curv[(long)a2.x * 16 + l];
    VecT v3 = curv[(long)a3.x * 16 + l];
    while (j + 4 < end) {
        int jn = j + 4;
        int2 b0 = (jn + 0 < end) ? ent[jn + 0] : make_int2(0, 0);
        int2 b1 = (jn + 1 < end) ? ent[jn + 1] : make_int2(0, 0);
        int2 b2 = (jn + 2 < end) ? ent[jn + 2] : make_int2(0, 0);
        int2 b3 = (jn + 3 < end) ? ent[jn + 3] : make_int2(0, 0);
        VecT u0 = curv[(long)b0.x * 16 + l];
        VecT u1 = curv[(long)b1.x * 16 + l];
        VecT u2 = curv[(long)b2.x * 16 + l];
        VecT u3 = curv[(long)b3.x * 16 + l];
        acc += __int_as_float(a0.y) * tof32(v0);
        acc += __int_as_float(a1.y) * tof32(v1);
        acc += __int_as_float(a2.y) * tof32(v2);
        acc += __int_as_float(a3.y) * tof32(v3);
        a0 = b0; a1 = b1; a2 = b2; a3 = b3;
        v0 = u0; v1 = u1; v2 = u2; v3 = u3;
        j = jn;
    }
    acc += __int_as_float(a0.y) * tof32(v0);
    acc += __int_as_float(a1.y) * tof32(v1);
    acc += __int_as_float(a2.y) * tof32(v2);
    acc += __int_as_float(a3.y) * tof32(v3);

    long o4 = (long)row * 16 + l;
    if (MODE == 0) {
        ((half4v*)dstH)[o4] = __builtin_convertvector(acc, half4v);
    } else if (MODE == 1) {
        float4v e0 = tof32(((const half4v*)cur0H)[o4]);
        float4v e1 = tof32(((const half4v*)curH)[o4]);
        ((float4v*)dstF)[o4] = acc;              // e2 (fp32) for layer 3
        ((float4v*)out)[o4]  = e0 + e1 + acc;    // partial sum e0+e1+e2
    } else {
        float4v pv = ((const float4v*)out)[o4];
        ((float4v*)out)[o4] = 0.25f * (pv + acc);
    }
}

extern "C" void kernel_launch(void* const* d_in, const int* in_sizes, int n_in,
                              void* d_out, int out_size, void* d_ws, size_t ws_size,
                              hipStream_t stream) {
    const float* user_emb = (const float*)d_in[0];
    const float* item_emb = (const float*)d_in[1];
    const int*   edge_user = (const int*)d_in[2];
    const int*   edge_item = (const int*)d_in[3];
    const int*   s_row = (const int*)d_in[4];
    const int*   s_col = (const int*)d_in[5];
    const float* s_val = (const float*)d_in[6];
    float* out = (float*)d_out;

    const int U = in_sizes[0] / EMB_D;
    const int I = in_sizes[1] / EMB_D;
    const int M = U + I;
    const int E = in_sizes[2];
    const int S = in_sizes[4];
    const long MD = (long)M * EMB_D;
    const long NT = 2L * E + S;       // merged CSR entries

    // workspace carve-up, 16B-aligned chunks
    char* p = (char*)d_ws;
    auto carve = [&](long bytes) {
        char* q = p;
        p += (bytes + 15) & ~15L;
        return q;
    };
    _Float16* cur0H  = (_Float16*)carve(MD * sizeof(_Float16));  // e0 (fp16)
    _Float16* cur1H  = (_Float16*)carve(MD * sizeof(_Float16));  // e1 (fp16)
    float*    bufC   = (float*)carve(MD * sizeof(float));        // e2 (fp32)
    float*    norm   = (float*)carve((long)M * sizeof(float));
    int*   deg_all = (int*)carve((long)(M + I) * sizeof(int));   // deg | degs adjacent
    int*   deg     = deg_all;
    int*   degs    = deg_all + M;
    int*   incl    = (int*)carve((long)M * sizeof(int));
    int*   rowptr  = (int*)carve((long)(M + 1) * sizeof(int));
    int*   cursor  = (int*)carve((long)M * sizeof(int));
    int*   bsum    = (int*)carve(256 * sizeof(int));
    int2*  ent     = (int2*)carve((NT + 8) * sizeof(int2));      // +slack for pipeline

    const int nb1 = (M + 1023) / 1024;
    const int nbE = (E + 255) / 256;
    const int nbS = (S + 255) / 256;
    const int nbMax = (nbE > nbS) ? nbE : nbS;

    // 1) fused partitioned degrees (one memset: deg|degs adjacent)
    hipMemsetAsync(deg_all, 0, (size_t)(M + I) * sizeof(int), stream);
    deg_part_kernel<<<NCLS * nbMax, 256, 0, stream>>>(edge_user, edge_item, E, U,
                                                      s_row, S, M, deg, degs);

    // 2) single scan over combined row lengths (also emits norm)
    scan_block<<<nb1, 1024, 0, stream>>>(deg, degs, U, M, norm, incl, bsum);
    scan_bsum<<<1, 256, 0, stream>>>(bsum, nb1);
    finalize_rowptr<<<(M + 256) / 256, 256, 0, stream>>>(incl, deg, degs, bsum, U, M,
                                                         rowptr, cursor);

    // 3) merged partitioned scatter into the single CSR
    scatter_all<<<NCLS * (nbE + nbS), 256, 0, stream>>>(edge_user, edge_item, E, nbE,
                                                        s_row, s_col, s_val, S,
                                                        U, M, norm, cursor, ent);

    // 4) init cur0 (fp16)
    init_kernel<<<2048, 256, 0, stream>>>((const float4v*)user_emb, (const float4v*)item_emb,
                                          (long)U * (EMB_D / 4), MD / 4, (half4v*)cur0H);

    // 5) L=3 gather layers: fp16 reads for layers 1-2, fp32 for layer 3
    const int gblocks = (int)(((long)M * 16 + 255) / 256);
    gather_kernel<0><<<gblocks, 256, 0, stream>>>(rowptr, ent, cur0H, nullptr, nullptr,
                                                  cur1H, nullptr, nullptr, U, I, M);
    gather_kernel<1><<<gblocks, 256, 0, stream>>>(rowptr, ent, cur1H, nullptr, cur0H,
                                                  nullptr, bufC, out, U, I, M);
    gather_kernel<2><<<gblocks, 256, 0, stream>>>(rowptr, ent, nullptr, bufC, nullptr,
                                                  nullptr, nullptr, out, U, I, M);
}